// Round 11
// baseline (328.390 us; speedup 1.0000x reference)
//
#include <hip/hip_runtime.h>
#include <hip/hip_bf16.h>

#define NN 2048
#define BB 8
#define FD 256
#define NEG_SLOPE 0.2f
#define EPSV 1e-7f

typedef __bf16 bf16x8 __attribute__((ext_vector_type(8)));
typedef __bf16 bf16x4 __attribute__((ext_vector_type(4)));
typedef float f32x4 __attribute__((ext_vector_type(4)));

// async 16B global -> LDS (lds base wave-uniform; HW scatters dest = base + lane*16)
__device__ __forceinline__ void gload16(const __bf16* g, __bf16* l) {
    __builtin_amdgcn_global_load_lds((const __attribute__((address_space(1))) unsigned int*)g,
                                     (__attribute__((address_space(3))) unsigned int*)l,
                                     16, 0, 0);
}

// ---------------- K1: WT[o][f] = bf16(W[f][o]) ----------------
__global__ __launch_bounds__(256) void k1_prep(const float* __restrict__ W,
                                               __bf16* __restrict__ WT) {
    int idx = blockIdx.x * 256 + threadIdx.x;   // 256 blocks
    int o = idx >> 8, f = idx & 255;
    WT[idx] = (__bf16)W[f * FD + o];
}

// ---------------- K2: Wh = x @ W (bf16 MFMA) + fused s_src/s_dst scores --------
__global__ __launch_bounds__(256) void k2_whgemm(const float* __restrict__ x,
                                                 const __bf16* __restrict__ WT,
                                                 const float* __restrict__ a_w,
                                                 float* __restrict__ Wh,
                                                 float* __restrict__ s_src,
                                                 float* __restrict__ s_dst) {
    const int wave = threadIdx.x >> 6;
    const int lane = threadIdx.x & 63;
    const int row0 = blockIdx.x * 32 + (wave >> 1) * 16;
    const int ohalf = (wave & 1) * 128;
    const int m = lane & 15;
    const int quad = lane >> 4;
    const int row = row0 + m;
    const float* xrow = x + (size_t)row * FD + quad * 8;

    f32x4 acc[8];
#pragma unroll
    for (int n = 0; n < 8; ++n) acc[n] = (f32x4){0.f, 0.f, 0.f, 0.f};

    for (int k0 = 0; k0 < FD; k0 += 32) {
        float4 xa = *(const float4*)(xrow + k0);
        float4 xb = *(const float4*)(xrow + k0 + 4);
        bf16x8 af;
        af[0] = (__bf16)xa.x; af[1] = (__bf16)xa.y; af[2] = (__bf16)xa.z; af[3] = (__bf16)xa.w;
        af[4] = (__bf16)xb.x; af[5] = (__bf16)xb.y; af[6] = (__bf16)xb.z; af[7] = (__bf16)xb.w;
#pragma unroll
        for (int n = 0; n < 8; ++n) {
            int o = ohalf + n * 16 + m;
            bf16x8 bf = *(const bf16x8*)(WT + o * FD + k0 + quad * 8);
            acc[n] = __builtin_amdgcn_mfma_f32_16x16x32_bf16(af, bf, acc[n], 0, 0, 0);
        }
    }
#pragma unroll
    for (int n = 0; n < 8; ++n) {
        int o = ohalf + n * 16 + m;
#pragma unroll
        for (int r = 0; r < 4; ++r) {
            Wh[(size_t)(row0 + quad * 4 + r) * FD + o] = acc[n][r];
        }
    }

    float psrc[4] = {0.f, 0.f, 0.f, 0.f};
    float pdst[4] = {0.f, 0.f, 0.f, 0.f};
#pragma unroll
    for (int n = 0; n < 8; ++n) {
        int o = ohalf + n * 16 + m;
        float awS = a_w[o], awD = a_w[FD + o];
#pragma unroll
        for (int r = 0; r < 4; ++r) {
            psrc[r] += acc[n][r] * awS;
            pdst[r] += acc[n][r] * awD;
        }
    }
#pragma unroll
    for (int off = 1; off <= 8; off <<= 1) {
#pragma unroll
        for (int r = 0; r < 4; ++r) {
            psrc[r] += __shfl_xor(psrc[r], off, 64);
            pdst[r] += __shfl_xor(pdst[r], off, 64);
        }
    }
    __shared__ float sS[2][2][16], sD[2][2][16];
    if (m == 0) {
        int rp = wave >> 1, oh = wave & 1;
#pragma unroll
        for (int r = 0; r < 4; ++r) {
            sS[rp][oh][quad * 4 + r] = psrc[r];
            sD[rp][oh][quad * 4 + r] = pdst[r];
        }
    }
    __syncthreads();
    if (threadIdx.x < 32) {
        int rp = threadIdx.x >> 4, idx = threadIdx.x & 15;
        int orow = blockIdx.x * 32 + rp * 16 + idx;
        s_src[orow] = sS[rp][0][idx] + sS[rp][1][idx];
        s_dst[orow] = sD[rp][0][idx] + sD[rp][1][idx];
    }
}

// ---------------- K4: den_part partial sums + Apack (4 adjacency bits / byte) ----
__global__ __launch_bounds__(256) void k4_den(const float* __restrict__ A,
                                              const float* __restrict__ s_src,
                                              const float* __restrict__ s_dst,
                                              const float* __restrict__ a_bp,
                                              float* __restrict__ den_part,
                                              unsigned char* __restrict__ Apack) {
    const int blk = blockIdx.x;
    const int b = blk & 7;
    const int jhalf = (blk >> 3) & 1;
    const int isp = blk >> 4;
    const int i0 = isp * 32;
    const int j = jhalf * 1024 + threadIdx.x * 4;
    __shared__ float ss[32];
    if (threadIdx.x < 32) ss[threadIdx.x] = s_src[b * NN + i0 + threadIdx.x] + a_bp[0];
    __syncthreads();
    float4 sd = *(const float4*)(s_dst + b * NN + j);
    float ax = 0.f, ay = 0.f, az = 0.f, aw = 0.f;
    const float* Ap = A + ((size_t)b * NN + i0) * NN + j;
    unsigned char* Pk = Apack + ((size_t)(b * NN + i0)) * 512 + jhalf * 256 + threadIdx.x;
#pragma unroll 8
    for (int i = 0; i < 32; ++i) {
        float4 a = *(const float4*)(Ap + (size_t)i * NN);
        float si = ss[i];
        float e0 = si + sd.x; e0 = e0 > 0.f ? e0 : NEG_SLOPE * e0;
        float e1 = si + sd.y; e1 = e1 > 0.f ? e1 : NEG_SLOPE * e1;
        float e2 = si + sd.z; e2 = e2 > 0.f ? e2 : NEG_SLOPE * e2;
        float e3 = si + sd.w; e3 = e3 > 0.f ? e3 : NEG_SLOPE * e3;
        ax += a.x * __expf(e0);
        ay += a.y * __expf(e1);
        az += a.z * __expf(e2);
        aw += a.w * __expf(e3);
        unsigned nib = (a.x > 0.5f ? 1u : 0u) | (a.y > 0.5f ? 2u : 0u) |
                       (a.z > 0.5f ? 4u : 0u) | (a.w > 0.5f ? 8u : 0u);
        Pk[(size_t)i * 512] = (unsigned char)nib;
    }
    float4 r = (float4){ax, ay, az, aw};
    *(float4*)(den_part + (size_t)isp * (BB * NN) + b * NN + j) = r;
}

// ---------------- K5: WhT[b][o][j] = bf16( Wh[b][j][o] / (sum(den_part)+eps) ) ----
__global__ __launch_bounds__(256) void k5_wht(const float* __restrict__ Wh,
                                              const float* __restrict__ den_part,
                                              __bf16* __restrict__ WhT) {
    const int b = blockIdx.z;
    const int j0 = blockIdx.x * 64;
    const int o0 = blockIdx.y * 64;
    __shared__ float tile[64][65];
    __shared__ float invd[64];
    if (threadIdx.x < 64) {
        float s = 0.f;
        const float* dp = den_part + b * NN + j0 + threadIdx.x;
#pragma unroll 8
        for (int sI = 0; sI < 64; ++sI) s += dp[(size_t)sI * (BB * NN)];
        invd[threadIdx.x] = 1.f / (s + EPSV);
    }
    __syncthreads();
    int jr = threadIdx.x >> 4, oc = (threadIdx.x & 15) * 4;
#pragma unroll
    for (int p = 0; p < 4; ++p) {
        int jj = jr + p * 16;
        float4 v = *(const float4*)(Wh + (size_t)(b * NN + j0 + jj) * FD + o0 + oc);
        float s = invd[jj];
        tile[jj][oc + 0] = v.x * s;
        tile[jj][oc + 1] = v.y * s;
        tile[jj][oc + 2] = v.z * s;
        tile[jj][oc + 3] = v.w * s;
    }
    __syncthreads();
    int ow = threadIdx.x >> 4, jc = (threadIdx.x & 15) * 4;
#pragma unroll
    for (int p = 0; p < 4; ++p) {
        int o = ow + p * 16;
        bf16x4 wv;
        wv[0] = (__bf16)tile[jc + 0][o];
        wv[1] = (__bf16)tile[jc + 1][o];
        wv[2] = (__bf16)tile[jc + 2][o];
        wv[3] = (__bf16)tile[jc + 3][o];
        *(bf16x4*)(WhT + (size_t)(b * FD + o0 + o) * NN + j0 + jc) = wv;
    }
}

// ---------------- K6: BARRIER-FREE fused GEMM: out = (A*exp(lrelu(e))) @ WhT^T ----
// grid 1024: b = blk&7 (XCD affinity), itile = blk>>3 (0..127). Block = 16i x 256o,
// 4 waves; wave w owns o-cols [w*64, +64) with its OWN double-buffered LDS B tile
// (no cross-wave sharing -> zero __syncthreads; sync is the compiler's vmcnt wait
// before ds_read of the buffer staged one step earlier). A-fragments built fully
// in registers from Apack (2 B/lane, L1) + s_dst (L1) in MFMA A-layout.
__global__ __launch_bounds__(256) void k6_out(const unsigned char* __restrict__ Apack,
                                              const __bf16* __restrict__ WhT,
                                              const float* __restrict__ s_src,
                                              const float* __restrict__ s_dst,
                                              const float* __restrict__ a_bp,
                                              float* __restrict__ out) {
    __shared__ __bf16 Bt[4][2][64 * 32];   // per-wave dbuf B tiles: 4 x 2 x 4 KiB = 32 KiB
    const int blk = blockIdx.x;
    const int b = blk & 7;
    const int itile = blk >> 3;
    const int i0 = itile * 16;
    const int t = threadIdx.x;
    const int w = t >> 6, lane = t & 63;
    const int m = lane & 15, quad = lane >> 4;
    const int o0 = w * 64;

    // staging: call c covers B-rows [o0 + c*16, +16); lane -> row +(lane>>2), 16B chunk lane&3
    const __bf16* gB = WhT + ((size_t)(b * FD + o0 + (lane >> 2))) * NN + (lane & 3) * 8;
    __bf16* lB = &Bt[w][0][0];             // wave-uniform
    // per-lane A-side sources (registers path, no LDS)
    const float ssr = s_src[b * NN + i0 + m] + a_bp[0];
    const unsigned char* Apb = Apack + ((size_t)(b * NN + i0 + m)) * 512 + quad * 2;
    const float* sdp = s_dst + b * NN + quad * 8;

    // stage step 0 into buf 0
#pragma unroll
    for (int c = 0; c < 4; ++c)
        gload16(gB + (size_t)(c * 16) * NN, lB + c * 512);

    f32x4 acc[4];
#pragma unroll
    for (int n = 0; n < 4; ++n) acc[n] = (f32x4){0.f, 0.f, 0.f, 0.f};

    const __bf16* Br = lB + m * 32 + quad * 8;

    for (int kk = 0; kk < 64; ++kk) {
        const int cur = kk & 1, nb = cur ^ 1;
        // (1) read current-buffer B frags (compiler emits the vmcnt wait here,
        //     draining exactly the staging issued one step ago)
        const __bf16* Bk = Br + cur * 2048;
        bf16x8 bf0 = *(const bf16x8*)(Bk);
        bf16x8 bf1 = *(const bf16x8*)(Bk + 16 * 32);
        bf16x8 bf2 = *(const bf16x8*)(Bk + 32 * 32);
        bf16x8 bf3 = *(const bf16x8*)(Bk + 48 * 32);
        // (2) stage next step's B into the other buffer (flies during (3)+(4))
        if (kk < 63) {
#pragma unroll
            for (int c = 0; c < 4; ++c)
                gload16(gB + (size_t)(c * 16) * NN + (kk + 1) * 32, lB + nb * 2048 + c * 512);
        }
        // (3) build A-fragment in registers: 8 j-values at kk*32 + quad*8
        unsigned short av = *(const unsigned short*)(Apb + kk * 8);
        unsigned abits = (av & 0x0Fu) | ((av >> 4) & 0xF0u);   // bit d (0..7) = A(row, j+d)
        float4 q0 = *(const float4*)(sdp + kk * 32);
        float4 q1 = *(const float4*)(sdp + kk * 32 + 4);
        bf16x8 af;
        float e;
        e = ssr + q0.x; e = e > 0.f ? e : NEG_SLOPE * e; af[0] = (__bf16)((abits &   1u) ? __expf(e) : 0.f);
        e = ssr + q0.y; e = e > 0.f ? e : NEG_SLOPE * e; af[1] = (__bf16)((abits &   2u) ? __expf(e) : 0.f);
        e = ssr + q0.z; e = e > 0.f ? e : NEG_SLOPE * e; af[2] = (__bf16)((abits &   4u) ? __expf(e) : 0.f);
        e = ssr + q0.w; e = e > 0.f ? e : NEG_SLOPE * e; af[3] = (__bf16)((abits &   8u) ? __expf(e) : 0.f);
        e = ssr + q1.x; e = e > 0.f ? e : NEG_SLOPE * e; af[4] = (__bf16)((abits &  16u) ? __expf(e) : 0.f);
        e = ssr + q1.y; e = e > 0.f ? e : NEG_SLOPE * e; af[5] = (__bf16)((abits &  32u) ? __expf(e) : 0.f);
        e = ssr + q1.z; e = e > 0.f ? e : NEG_SLOPE * e; af[6] = (__bf16)((abits &  64u) ? __expf(e) : 0.f);
        e = ssr + q1.w; e = e > 0.f ? e : NEG_SLOPE * e; af[7] = (__bf16)((abits & 128u) ? __expf(e) : 0.f);
        // (4) MFMA
        acc[0] = __builtin_amdgcn_mfma_f32_16x16x32_bf16(af, bf0, acc[0], 0, 0, 0);
        acc[1] = __builtin_amdgcn_mfma_f32_16x16x32_bf16(af, bf1, acc[1], 0, 0, 0);
        acc[2] = __builtin_amdgcn_mfma_f32_16x16x32_bf16(af, bf2, acc[2], 0, 0, 0);
        acc[3] = __builtin_amdgcn_mfma_f32_16x16x32_bf16(af, bf3, acc[3], 0, 0, 0);
    }

#pragma unroll
    for (int n = 0; n < 4; ++n) {
        int o = o0 + n * 16 + m;
#pragma unroll
        for (int rr = 0; rr < 4; ++rr) {
            int orow = i0 + quad * 4 + rr;
            out[((size_t)b * NN + orow) * FD + o] = acc[n][rr];
        }
    }
}

extern "C" void kernel_launch(void* const* d_in, const int* in_sizes, int n_in,
                              void* d_out, int out_size, void* d_ws, size_t ws_size,
                              hipStream_t stream) {
    const float* A   = (const float*)d_in[0];
    const float* x   = (const float*)d_in[1];
    const float* W   = (const float*)d_in[2];
    const float* a_w = (const float*)d_in[3];
    const float* a_b = (const float*)d_in[4];
    float* out = (float*)d_out;

    char* ws = (char*)d_ws;
    __bf16* WT      = (__bf16*)ws;                      // 131,072 B
    float*  Wh      = (float*)(ws + 131072);            // 16,777,216 B
    __bf16* WhT     = (__bf16*)(ws + 16908288);         // 8,388,608 B
    float*  s_src   = (float*)(ws + 25296896);          // 65,536 B
    float*  s_dst   = (float*)(ws + 25362432);          // 65,536 B
    float*  den_part= (float*)(ws + 25427968);          // 64*16384*4 = 4,194,304 B
    unsigned char* Apack = (unsigned char*)(ws + 29622272); // 8*2048*512 = 8,388,608 B

    k1_prep<<<256, 256, 0, stream>>>(W, WT);
    k2_whgemm<<<512, 256, 0, stream>>>(x, WT, a_w, Wh, s_src, s_dst);
    k4_den<<<1024, 256, 0, stream>>>(A, s_src, s_dst, a_b, den_part, Apack);
    k5_wht<<<dim3(32, 4, 8), 256, 0, stream>>>(Wh, den_part, WhT);
    k6_out<<<1024, 256, 0, stream>>>(Apack, WhT, s_src, s_dst, a_b, out);
}